// Round 5
// baseline (518.803 us; speedup 1.0000x reference)
//
#include <hip/hip_runtime.h>

// SemNN — twin-tower masked-pool encoder + classifier.
// B=4096, S=128, D=512, VOCAB=50000, NUM_LABELS=3.
//
// Round-4 diagnosis: rounds 2/3/4 produced BIT-IDENTICAL error 5.700684e-02
// across three different mask-decoding schemes => mask handling correct, bug
// elsewhere. Quantitative analysis: error == expected absmax of comparing
// f32 words [bf16_lo|bf16_hi] (i.e. ~logit_{2j+1}) against ref logit_j
// (0.053 predicted, 0.057 observed) => d_out is FLOAT32 (the reference's
// output dtype), and my bf16 output writes were being misread. Float INPUTS
// are bf16 (that's the harness's _any_bf16); masks int32-or-byte; ids int32.
// Fix: logits kernel writes f32. Everything else frozen.
//
// ws usage: exactly 16 MB (two 8 MB bf16 intermediate buffers).

typedef unsigned short u16;

__device__ __forceinline__ float bfu2f(u16 u) {
    union { unsigned int i; float f; } v;
    v.i = ((unsigned int)u) << 16;
    return v.f;
}

__device__ __forceinline__ u16 f2bfu(float f) {
    union { float f; unsigned int i; } v;
    v.f = f;
    unsigned int x = v.i;
    x += 0x7fffu + ((x >> 16) & 1u);   // RNE
    return (u16)(x >> 16);
}

// Wave-collective dtype detection; every lane of the wave returns flags:
//   bit0    : float tensors are bf16 (vs f32)
//   bits2-3 : mask type 0=int32, 1=byte-bool, 2=bf16, 3=f32
__device__ __forceinline__ int detect_wave(const u16* __restrict__ W,
                                           const unsigned int* __restrict__ m,
                                           int lane)
{
    int cnt = 0;
    int w01 = 1;      // all mask words in {0,1}
    int b01 = 1;      // all mask bytes in {0,1}
    int lo16 = 0;     // any low-half u16 == 0x3F80
    #pragma unroll
    for (int j = lane; j < 256; j += 64) {
        u16 u = W[1024 + 2 * j];
        int e = (u >> 7) & 0xFF;
        cnt += (e >= 0x6A && e <= 0x7E) ? 1 : 0;

        unsigned int v = m[j];
        w01 &= (v <= 1u) ? 1 : 0;
        b01 &= ((v & ~0x01010101u) == 0u) ? 1 : 0;
        lo16 |= ((v & 0xFFFFu) == 0x3F80u) ? 1 : 0;
    }
    #pragma unroll
    for (int off = 32; off > 0; off >>= 1) {
        cnt  += __shfl_down(cnt, off);
        w01  &= __shfl_down(w01, off);
        b01  &= __shfl_down(b01, off);
        lo16 |= __shfl_down(lo16, off);
    }
    int mtype;
    if (w01)        mtype = 0;
    else if (b01)   mtype = 1;
    else if (lo16)  mtype = 2;
    else            mtype = 3;
    int fl = ((cnt >= 128) ? 1 : 0) | (mtype << 2);
    return __shfl(fl, 0);
}

__device__ __forceinline__ int mask_nonzero(const void* __restrict__ msk,
                                            int idx, int mtype)
{
    switch (mtype) {
        case 0:  return ((const int*)msk)[idx] != 0;
        case 1:  return ((const unsigned char*)msk)[idx] != 0;
        case 2:  return ((const u16*)msk)[idx] != 0;
        default: return ((const unsigned int*)msk)[idx] != 0u;  // f32 bits
    }
}

// ---------------------------------------------------------------------------
// Kernel 1: embedding gather + masked sum-pool -> P (bf16) [8192,512].
// One block per (side,row); 128 threads; thread t owns cols 4t..4t+3.
// Active ids compacted into LDS -> branch-free gather loop.
// ---------------------------------------------------------------------------
__global__ __launch_bounds__(128) void pool_kernel(
    const int* __restrict__ ids_a, const int* __restrict__ ids_b,
    const void* __restrict__ mask_a, const void* __restrict__ mask_b,
    const void* __restrict__ W, u16* __restrict__ P)
{
    __shared__ int s_ids[128];
    __shared__ int s_cnt;
    __shared__ int s_flags;
    const int t = threadIdx.x;

    if (t == 0) s_cnt = 0;
    if (t < 64) {
        int fl = detect_wave((const u16*)W, (const unsigned int*)mask_a, t);
        if (t == 0) s_flags = fl;
    }
    __syncthreads();
    const int  flags = s_flags;
    const bool isbf  = (flags & 1) != 0;
    const int  mtype = (flags >> 2) & 3;

    const int row  = blockIdx.x & 4095;
    const int side = blockIdx.x >> 12;
    const int* __restrict__ ids = side ? ids_b : ids_a;
    const void* __restrict__ msk = side ? mask_b : mask_a;

    int id = ids[row * 128 + t];
    int mk = mask_nonzero(msk, row * 128 + t, mtype);
    if (mk) {
        int idx = atomicAdd(&s_cnt, 1);
        s_ids[idx] = id;
    }
    __syncthreads();
    const int cnt = s_cnt;

    float4 acc = {0.f, 0.f, 0.f, 0.f};
    if (isbf) {
        const u16* Wb = (const u16*)W;
        for (int j = 0; j < cnt; ++j) {
            ushort4 r4 = *(const ushort4*)(Wb + (size_t)s_ids[j] * 512 + t * 4);
            acc.x += bfu2f(r4.x); acc.y += bfu2f(r4.y);
            acc.z += bfu2f(r4.z); acc.w += bfu2f(r4.w);
        }
    } else {
        const float* Wf = (const float*)W;
        for (int j = 0; j < cnt; ++j) {
            float4 r4 = *(const float4*)(Wf + (size_t)s_ids[j] * 512 + t * 4);
            acc.x += r4.x; acc.y += r4.y; acc.z += r4.z; acc.w += r4.w;
        }
    }
    ushort4 o = { f2bfu(acc.x), f2bfu(acc.y), f2bfu(acc.z), f2bfu(acc.w) };
    *(ushort4*)(P + (size_t)blockIdx.x * 512 + t * 4) = o;
}

// ---------------------------------------------------------------------------
// Kernel 2: tiled GEMM + bias + tanh.  C = tanh(Acat @ B + bias), bf16 out.
// Acat[m,k] = A[m*512+k] (k<K1) else A2[m*512+(k-K1)]  -- concat support.
// A/A2/C bf16 (ours). B/bias external: dtype per detected flag.
// Tile 64x64, BK=16, 256 thr, 4x4 microtile, fp32 accumulate.
// ---------------------------------------------------------------------------
__global__ __launch_bounds__(256) void gemm_kernel(
    const u16* __restrict__ A, const u16* __restrict__ A2, int K1,
    const void* __restrict__ B, const void* __restrict__ bias,
    u16* __restrict__ C, int N, int K,
    const u16* __restrict__ Wdet, const unsigned int* __restrict__ Mdet)
{
    __shared__ __align__(16) float As[16][68];
    __shared__ __align__(16) float Bs[16][68];
    __shared__ int s_flags;

    const int tx = threadIdx.x, ty = threadIdx.y;
    const int tid = ty * 16 + tx;

    if (tid < 64) {
        int fl = detect_wave(Wdet, Mdet, tid);
        if (tid == 0) s_flags = fl;
    }
    __syncthreads();
    const bool isbf = (s_flags & 1) != 0;

    const int m0 = blockIdx.y * 64;
    const int n0 = blockIdx.x * 64;

    const int ar = tid >> 2;          // A: row within tile
    const int ac = (tid & 3) * 4;     // A: k within BK
    const int br = tid >> 4;          // B: k within BK
    const int bc = (tid & 15) * 4;    // B: col within tile

    float acc[4][4] = {};

    for (int k0 = 0; k0 < K; k0 += 16) {
        const int kg = k0 + ac;       // K1 multiple of 16 -> uniform predicate
        const u16* Ap = (kg < K1) ? (A  + (size_t)(m0 + ar) * 512 + kg)
                                  : (A2 + (size_t)(m0 + ar) * 512 + (kg - K1));
        ushort4 av = *(const ushort4*)Ap;
        As[ac + 0][ar] = bfu2f(av.x);
        As[ac + 1][ar] = bfu2f(av.y);
        As[ac + 2][ar] = bfu2f(av.z);
        As[ac + 3][ar] = bfu2f(av.w);

        float4 bf4;
        if (isbf) {
            ushort4 bv = *(const ushort4*)((const u16*)B + (size_t)(k0 + br) * N + n0 + bc);
            bf4.x = bfu2f(bv.x); bf4.y = bfu2f(bv.y);
            bf4.z = bfu2f(bv.z); bf4.w = bfu2f(bv.w);
        } else {
            bf4 = *(const float4*)((const float*)B + (size_t)(k0 + br) * N + n0 + bc);
        }
        *(float4*)&Bs[br][bc] = bf4;

        __syncthreads();
        #pragma unroll
        for (int kk = 0; kk < 16; ++kk) {
            float4 a4 = *(const float4*)&As[kk][ty * 4];
            float4 b4 = *(const float4*)&Bs[kk][tx * 4];
            float a_[4] = {a4.x, a4.y, a4.z, a4.w};
            float b_[4] = {b4.x, b4.y, b4.z, b4.w};
            #pragma unroll
            for (int i = 0; i < 4; ++i)
                #pragma unroll
                for (int j = 0; j < 4; ++j)
                    acc[i][j] += a_[i] * b_[j];
        }
        __syncthreads();
    }

    #pragma unroll
    for (int i = 0; i < 4; ++i) {
        const int m = m0 + ty * 4 + i;
        ushort4 cv;
        u16* cp = &cv.x;
        #pragma unroll
        for (int j = 0; j < 4; ++j) {
            const int n = n0 + tx * 4 + j;
            float bsv = isbf ? bfu2f(((const u16*)bias)[n]) : ((const float*)bias)[n];
            cp[j] = f2bfu(tanhf(acc[i][j] + bsv));
        }
        *(ushort4*)(C + (size_t)m * N + n0 + tx * 4) = cv;
    }
}

// ---------------------------------------------------------------------------
// Kernel 3: logits GEMV  out[m,0:3] = H[m,:] @ W2 + b2 -> FLOAT32 out.
// One wave per row.
// ---------------------------------------------------------------------------
__global__ __launch_bounds__(64) void logits_kernel(
    const u16* __restrict__ H, const void* __restrict__ W2,
    const void* __restrict__ b2, float* __restrict__ out,
    const u16* __restrict__ Wdet, const unsigned int* __restrict__ Mdet)
{
    const int lane = threadIdx.x;
    const int fl = detect_wave(Wdet, Mdet, lane);
    const bool isbf = (fl & 1) != 0;

    const int m = blockIdx.x;
    const u16* h = H + (size_t)m * 512;

    float a0 = 0.f, a1 = 0.f, a2 = 0.f;
    #pragma unroll
    for (int k = lane; k < 512; k += 64) {
        float x = bfu2f(h[k]);
        float w0, w1, w2;
        if (isbf) {
            const u16* Wb = (const u16*)W2;
            w0 = bfu2f(Wb[k * 3 + 0]); w1 = bfu2f(Wb[k * 3 + 1]); w2 = bfu2f(Wb[k * 3 + 2]);
        } else {
            const float* Wf = (const float*)W2;
            w0 = Wf[k * 3 + 0]; w1 = Wf[k * 3 + 1]; w2 = Wf[k * 3 + 2];
        }
        a0 += x * w0; a1 += x * w1; a2 += x * w2;
    }
    #pragma unroll
    for (int off = 32; off > 0; off >>= 1) {
        a0 += __shfl_down(a0, off);
        a1 += __shfl_down(a1, off);
        a2 += __shfl_down(a2, off);
    }
    if (lane == 0) {
        float b0, b1, b2v;
        if (isbf) {
            const u16* bb = (const u16*)b2;
            b0 = bfu2f(bb[0]); b1 = bfu2f(bb[1]); b2v = bfu2f(bb[2]);
        } else {
            const float* bf = (const float*)b2;
            b0 = bf[0]; b1 = bf[1]; b2v = bf[2];
        }
        out[m * 3 + 0] = a0 + b0;
        out[m * 3 + 1] = a1 + b1;
        out[m * 3 + 2] = a2 + b2v;
    }
}

// ---------------------------------------------------------------------------
extern "C" void kernel_launch(void* const* d_in, const int* in_sizes, int n_in,
                              void* d_out, int out_size, void* d_ws, size_t ws_size,
                              hipStream_t stream)
{
    const int* ids_a  = (const int*)d_in[0];
    const int* ids_b  = (const int*)d_in[1];
    const void* mask_a = d_in[2];
    const void* mask_b = d_in[3];
    const void* W_emb  = d_in[4];
    const void* enc_w1 = d_in[5];
    const void* enc_b1 = d_in[6];
    const void* enc_w2 = d_in[7];
    const void* enc_b2 = d_in[8];
    const void* cls_w1 = d_in[9];
    const void* cls_b1 = d_in[10];
    const void* cls_w2 = d_in[11];
    const void* cls_b2 = d_in[12];

    const u16* Wdet = (const u16*)W_emb;
    const unsigned int* Mdet = (const unsigned int*)mask_a;

    u16* buf0 = (u16*)d_ws;                          // 8192*512 bf16 = 8 MB
    u16* buf1 = buf0 + (size_t)8192 * 512;           // 8 MB  (total = 16 MB exactly)

    // pooled -> buf0 (rows 0..4095 side a, 4096..8191 side b)
    pool_kernel<<<8192, 128, 0, stream>>>(ids_a, ids_b, mask_a, mask_b, W_emb, buf0);

    // X1 = tanh(P @ enc_w1 + b1) -> buf1
    gemm_kernel<<<dim3(8, 128), dim3(16, 16), 0, stream>>>(
        buf0, buf0, 512, enc_w1, enc_b1, buf1, 512, 512, Wdet, Mdet);

    // X2 = tanh(X1 @ enc_w2 + b2) -> buf0
    gemm_kernel<<<dim3(8, 128), dim3(16, 16), 0, stream>>>(
        buf1, buf1, 512, enc_w2, enc_b2, buf0, 512, 512, Wdet, Mdet);

    // H = tanh([va | vb] @ cls_w1 + b1) -> buf1
    gemm_kernel<<<dim3(8, 64), dim3(16, 16), 0, stream>>>(
        buf0, buf0 + (size_t)4096 * 512, 512, cls_w1, cls_b1, buf1, 512, 1024, Wdet, Mdet);

    // logits -> d_out (f32)
    logits_kernel<<<4096, 64, 0, stream>>>(buf1, cls_w2, cls_b2, (float*)d_out, Wdet, Mdet);
}

// Round 6
// 404.650 us; speedup vs baseline: 1.2821x; 1.2821x over previous
//
#include <hip/hip_runtime.h>

// SemNN — twin-tower masked-pool encoder + classifier.
// B=4096, S=128, D=512, VOCAB=50000, NUM_LABELS=3.
// Confirmed (round-5 PASS): float inputs bf16, ids int32, masks int-like
// (detector handles all 4 encodings), output f32. ws usage: exactly 16 MB.
//
// Round 6 changes:
//  * GEMMs moved from fp32 VALU (37 TF, ~115us each) to bf16 MFMA
//    16x16x32 (m89/m91-verified fragment layouts). 128x64 block tile, BK=32,
//    4 waves (2x2), wave tile 64x32 = 4x2 MFMA tiles. B (weights, [K][N]
//    row-major) is transposed during LDS staging; LDS rows padded to 40 u16
//    (80 B) so fragment b128 reads are 2-way bank aliases (free per m136).
//  * pool gather loop unrolled x4 for memory-level parallelism.

typedef unsigned short u16;
typedef __attribute__((ext_vector_type(8))) short short8;
typedef __attribute__((ext_vector_type(4))) float f32x4;

__device__ __forceinline__ float bfu2f(u16 u) {
    union { unsigned int i; float f; } v;
    v.i = ((unsigned int)u) << 16;
    return v.f;
}

__device__ __forceinline__ u16 f2bfu(float f) {
    union { float f; unsigned int i; } v;
    v.f = f;
    unsigned int x = v.i;
    x += 0x7fffu + ((x >> 16) & 1u);   // RNE
    return (u16)(x >> 16);
}

// Wave-collective dtype detection; every lane of the wave returns flags:
//   bit0    : float tensors are bf16 (vs f32)
//   bits2-3 : mask type 0=int32, 1=byte-bool, 2=bf16, 3=f32
__device__ __forceinline__ int detect_wave(const u16* __restrict__ W,
                                           const unsigned int* __restrict__ m,
                                           int lane)
{
    int cnt = 0;
    int w01 = 1, b01 = 1, lo16 = 0;
    #pragma unroll
    for (int j = lane; j < 256; j += 64) {
        u16 u = W[1024 + 2 * j];
        int e = (u >> 7) & 0xFF;
        cnt += (e >= 0x6A && e <= 0x7E) ? 1 : 0;
        unsigned int v = m[j];
        w01 &= (v <= 1u) ? 1 : 0;
        b01 &= ((v & ~0x01010101u) == 0u) ? 1 : 0;
        lo16 |= ((v & 0xFFFFu) == 0x3F80u) ? 1 : 0;
    }
    #pragma unroll
    for (int off = 32; off > 0; off >>= 1) {
        cnt  += __shfl_down(cnt, off);
        w01  &= __shfl_down(w01, off);
        b01  &= __shfl_down(b01, off);
        lo16 |= __shfl_down(lo16, off);
    }
    int mtype;
    if (w01)        mtype = 0;
    else if (b01)   mtype = 1;
    else if (lo16)  mtype = 2;
    else            mtype = 3;
    int fl = ((cnt >= 128) ? 1 : 0) | (mtype << 2);
    return __shfl(fl, 0);
}

__device__ __forceinline__ int mask_nonzero(const void* __restrict__ msk,
                                            int idx, int mtype)
{
    switch (mtype) {
        case 0:  return ((const int*)msk)[idx] != 0;
        case 1:  return ((const unsigned char*)msk)[idx] != 0;
        case 2:  return ((const u16*)msk)[idx] != 0;
        default: return ((const unsigned int*)msk)[idx] != 0u;  // f32 bits
    }
}

// ---------------------------------------------------------------------------
// Kernel 1: embedding gather + masked sum-pool -> P (bf16) [8192,512].
// One block per (side,row); 128 threads; thread t owns cols 4t..4t+3.
// Gather loop unrolled x4 for MLP (VALUBusy was 7.6% -> latency-bound).
// ---------------------------------------------------------------------------
__global__ __launch_bounds__(128) void pool_kernel(
    const int* __restrict__ ids_a, const int* __restrict__ ids_b,
    const void* __restrict__ mask_a, const void* __restrict__ mask_b,
    const void* __restrict__ W, u16* __restrict__ P)
{
    __shared__ int s_ids[128];
    __shared__ int s_cnt;
    __shared__ int s_flags;
    const int t = threadIdx.x;

    if (t == 0) s_cnt = 0;
    if (t < 64) {
        int fl = detect_wave((const u16*)W, (const unsigned int*)mask_a, t);
        if (t == 0) s_flags = fl;
    }
    __syncthreads();
    const int  flags = s_flags;
    const bool isbf  = (flags & 1) != 0;
    const int  mtype = (flags >> 2) & 3;

    const int row  = blockIdx.x & 4095;
    const int side = blockIdx.x >> 12;
    const int* __restrict__ ids = side ? ids_b : ids_a;
    const void* __restrict__ msk = side ? mask_b : mask_a;

    int id = ids[row * 128 + t];
    int mk = mask_nonzero(msk, row * 128 + t, mtype);
    if (mk) {
        int idx = atomicAdd(&s_cnt, 1);
        s_ids[idx] = id;
    }
    __syncthreads();
    const int cnt = s_cnt;

    float4 acc = {0.f, 0.f, 0.f, 0.f};
    if (isbf) {
        const u16* Wb = (const u16*)W;
        int j = 0;
        for (; j + 4 <= cnt; j += 4) {
            ushort4 r0 = *(const ushort4*)(Wb + (size_t)s_ids[j + 0] * 512 + t * 4);
            ushort4 r1 = *(const ushort4*)(Wb + (size_t)s_ids[j + 1] * 512 + t * 4);
            ushort4 r2 = *(const ushort4*)(Wb + (size_t)s_ids[j + 2] * 512 + t * 4);
            ushort4 r3 = *(const ushort4*)(Wb + (size_t)s_ids[j + 3] * 512 + t * 4);
            acc.x += bfu2f(r0.x) + bfu2f(r1.x) + bfu2f(r2.x) + bfu2f(r3.x);
            acc.y += bfu2f(r0.y) + bfu2f(r1.y) + bfu2f(r2.y) + bfu2f(r3.y);
            acc.z += bfu2f(r0.z) + bfu2f(r1.z) + bfu2f(r2.z) + bfu2f(r3.z);
            acc.w += bfu2f(r0.w) + bfu2f(r1.w) + bfu2f(r2.w) + bfu2f(r3.w);
        }
        for (; j < cnt; ++j) {
            ushort4 r4 = *(const ushort4*)(Wb + (size_t)s_ids[j] * 512 + t * 4);
            acc.x += bfu2f(r4.x); acc.y += bfu2f(r4.y);
            acc.z += bfu2f(r4.z); acc.w += bfu2f(r4.w);
        }
    } else {
        const float* Wf = (const float*)W;
        for (int j = 0; j < cnt; ++j) {
            float4 r4 = *(const float4*)(Wf + (size_t)s_ids[j] * 512 + t * 4);
            acc.x += r4.x; acc.y += r4.y; acc.z += r4.z; acc.w += r4.w;
        }
    }
    ushort4 o = { f2bfu(acc.x), f2bfu(acc.y), f2bfu(acc.z), f2bfu(acc.w) };
    *(ushort4*)(P + (size_t)blockIdx.x * 512 + t * 4) = o;
}

// ---------------------------------------------------------------------------
// Kernel 2: bf16 MFMA GEMM + bias + tanh.  C = tanh(Acat @ B + bias).
// Acat[m,k] = A[m*512+k] (k<K1) else A2[m*512+(k-K1)].
// A/A2/C bf16; B/bias external dtype per detected flag.
// Block tile 128(M) x 64(N), BK=32, 256 threads = 4 waves (2x2),
// wave tile 64x32 = 4x2 tiles of 16x16. MFMA 16x16x32 bf16.
// Fragment layouts (m89/m91-verified):
//   A: m=lane&15, k=(lane>>4)*8+j     B: n=lane&15, k=(lane>>4)*8+j
//   D: col=lane&15, row=(lane>>4)*4+reg
// LDS rows padded to 40 u16 (80 B) -> 2-way bank aliasing on b128 frag reads
// (free, m136). B is transposed (k-major) during staging.
// ---------------------------------------------------------------------------
__global__ __launch_bounds__(256) void gemm_mfma(
    const u16* __restrict__ A, const u16* __restrict__ A2, int K1,
    const void* __restrict__ B, const void* __restrict__ bias,
    u16* __restrict__ C, int N, int K,
    const u16* __restrict__ Wdet, const unsigned int* __restrict__ Mdet)
{
    __shared__ __align__(16) u16 As[128 * 40];   // [m][k], row stride 40
    __shared__ __align__(16) u16 Bs[64 * 40];    // [n][k], row stride 40
    __shared__ int s_flags;

    const int tid  = threadIdx.x;
    const int lane = tid & 63;

    if (tid < 64) {
        int fl = detect_wave(Wdet, Mdet, tid);
        if (tid == 0) s_flags = fl;
    }
    __syncthreads();
    const bool isbf = (s_flags & 1) != 0;

    const int m0 = blockIdx.y * 128;
    const int n0 = blockIdx.x * 64;

    // wave position in block tile
    const int wid = tid >> 6;
    const int wm  = (wid & 1) * 64;    // wave m-offset
    const int wn  = (wid >> 1) * 32;   // wave n-offset

    // A staging: thread -> row ar = tid>>1, k-chunk ak = (tid&1)*16 (16 elems)
    const int ar = tid >> 1;
    const int ak = (tid & 1) * 16;
    // B staging: thread -> k = tid&31, n-base nb = (tid>>5)*8 (8 elems)
    const int bk = tid & 31;
    const int nb = (tid >> 5) * 8;

    // fragment read indices
    const int lm  = lane & 15;
    const int kc  = (lane >> 4) * 8;

    f32x4 acc[4][2];
    #pragma unroll
    for (int i = 0; i < 4; ++i)
        #pragma unroll
        for (int j = 0; j < 2; ++j)
            acc[i][j] = (f32x4){0.f, 0.f, 0.f, 0.f};

    for (int k0 = 0; k0 < K; k0 += 32) {
        // ---- global loads ----
        // A: 16 bf16 (two ushort8) at [m0+ar][k0+ak .. +15]; K1 % 16 == 0 so
        // each 16-chunk is entirely within one source half (uniform select).
        const int kg = k0 + ak;
        const u16* Ap = (kg < K1) ? (A  + (size_t)(m0 + ar) * 512 + kg)
                                  : (A2 + (size_t)(m0 + ar) * 512 + (kg - K1));
        ushort4 a0 = *(const ushort4*)(Ap + 0);
        ushort4 a1 = *(const ushort4*)(Ap + 4);
        ushort4 a2 = *(const ushort4*)(Ap + 8);
        ushort4 a3 = *(const ushort4*)(Ap + 12);

        // B: 8 values at [k0+bk][n0+nb .. +7]
        u16 bv[8];
        if (isbf) {
            const u16* Bp = (const u16*)B + (size_t)(k0 + bk) * N + n0 + nb;
            ushort4 b0 = *(const ushort4*)(Bp + 0);
            ushort4 b1 = *(const ushort4*)(Bp + 4);
            bv[0] = b0.x; bv[1] = b0.y; bv[2] = b0.z; bv[3] = b0.w;
            bv[4] = b1.x; bv[5] = b1.y; bv[6] = b1.z; bv[7] = b1.w;
        } else {
            const float* Bp = (const float*)B + (size_t)(k0 + bk) * N + n0 + nb;
            float4 b0 = *(const float4*)(Bp + 0);
            float4 b1 = *(const float4*)(Bp + 4);
            bv[0] = f2bfu(b0.x); bv[1] = f2bfu(b0.y); bv[2] = f2bfu(b0.z); bv[3] = f2bfu(b0.w);
            bv[4] = f2bfu(b1.x); bv[5] = f2bfu(b1.y); bv[6] = f2bfu(b1.z); bv[7] = f2bfu(b1.w);
        }

        __syncthreads();   // previous iteration's frag reads done

        // ---- LDS writes ----
        *(ushort4*)&As[ar * 40 + ak + 0]  = a0;
        *(ushort4*)&As[ar * 40 + ak + 4]  = a1;
        *(ushort4*)&As[ar * 40 + ak + 8]  = a2;
        *(ushort4*)&As[ar * 40 + ak + 12] = a3;
        #pragma unroll
        for (int i = 0; i < 8; ++i)
            Bs[(nb + i) * 40 + bk] = bv[i];   // transpose: [n][k]

        __syncthreads();

        // ---- fragments + MFMA ----
        short8 af[4], bf[2];
        #pragma unroll
        for (int i = 0; i < 4; ++i)
            af[i] = *(const short8*)&As[(wm + i * 16 + lm) * 40 + kc];
        #pragma unroll
        for (int j = 0; j < 2; ++j)
            bf[j] = *(const short8*)&Bs[(wn + j * 16 + lm) * 40 + kc];

        #pragma unroll
        for (int i = 0; i < 4; ++i)
            #pragma unroll
            for (int j = 0; j < 2; ++j)
                acc[i][j] = __builtin_amdgcn_mfma_f32_16x16x32_bf16(
                    af[i], bf[j], acc[i][j], 0, 0, 0);
    }

    // ---- epilogue: bias + tanh + bf16 store ----
    #pragma unroll
    for (int j = 0; j < 2; ++j) {
        const int n = n0 + wn + j * 16 + lm;
        const float bsv = isbf ? bfu2f(((const u16*)bias)[n])
                               : ((const float*)bias)[n];
        #pragma unroll
        for (int i = 0; i < 4; ++i) {
            #pragma unroll
            for (int r = 0; r < 4; ++r) {
                const int m = m0 + wm + i * 16 + (lane >> 4) * 4 + r;
                C[(size_t)m * N + n] = f2bfu(tanhf(acc[i][j][r] + bsv));
            }
        }
    }
}

// ---------------------------------------------------------------------------
// Kernel 3: logits GEMV  out[m,0:3] = H[m,:] @ W2 + b2 -> FLOAT32 out.
// One wave per row.
// ---------------------------------------------------------------------------
__global__ __launch_bounds__(64) void logits_kernel(
    const u16* __restrict__ H, const void* __restrict__ W2,
    const void* __restrict__ b2, float* __restrict__ out,
    const u16* __restrict__ Wdet, const unsigned int* __restrict__ Mdet)
{
    const int lane = threadIdx.x;
    const int fl = detect_wave(Wdet, Mdet, lane);
    const bool isbf = (fl & 1) != 0;

    const int m = blockIdx.x;
    const u16* h = H + (size_t)m * 512;

    float a0 = 0.f, a1 = 0.f, a2 = 0.f;
    #pragma unroll
    for (int k = lane; k < 512; k += 64) {
        float x = bfu2f(h[k]);
        float w0, w1, w2;
        if (isbf) {
            const u16* Wb = (const u16*)W2;
            w0 = bfu2f(Wb[k * 3 + 0]); w1 = bfu2f(Wb[k * 3 + 1]); w2 = bfu2f(Wb[k * 3 + 2]);
        } else {
            const float* Wf = (const float*)W2;
            w0 = Wf[k * 3 + 0]; w1 = Wf[k * 3 + 1]; w2 = Wf[k * 3 + 2];
        }
        a0 += x * w0; a1 += x * w1; a2 += x * w2;
    }
    #pragma unroll
    for (int off = 32; off > 0; off >>= 1) {
        a0 += __shfl_down(a0, off);
        a1 += __shfl_down(a1, off);
        a2 += __shfl_down(a2, off);
    }
    if (lane == 0) {
        float b0, b1, b2v;
        if (isbf) {
            const u16* bb = (const u16*)b2;
            b0 = bfu2f(bb[0]); b1 = bfu2f(bb[1]); b2v = bfu2f(bb[2]);
        } else {
            const float* bf = (const float*)b2;
            b0 = bf[0]; b1 = bf[1]; b2v = bf[2];
        }
        out[m * 3 + 0] = a0 + b0;
        out[m * 3 + 1] = a1 + b1;
        out[m * 3 + 2] = a2 + b2v;
    }
}

// ---------------------------------------------------------------------------
extern "C" void kernel_launch(void* const* d_in, const int* in_sizes, int n_in,
                              void* d_out, int out_size, void* d_ws, size_t ws_size,
                              hipStream_t stream)
{
    const int* ids_a  = (const int*)d_in[0];
    const int* ids_b  = (const int*)d_in[1];
    const void* mask_a = d_in[2];
    const void* mask_b = d_in[3];
    const void* W_emb  = d_in[4];
    const void* enc_w1 = d_in[5];
    const void* enc_b1 = d_in[6];
    const void* enc_w2 = d_in[7];
    const void* enc_b2 = d_in[8];
    const void* cls_w1 = d_in[9];
    const void* cls_b1 = d_in[10];
    const void* cls_w2 = d_in[11];
    const void* cls_b2 = d_in[12];

    const u16* Wdet = (const u16*)W_emb;
    const unsigned int* Mdet = (const unsigned int*)mask_a;

    u16* buf0 = (u16*)d_ws;                          // 8192*512 bf16 = 8 MB
    u16* buf1 = buf0 + (size_t)8192 * 512;           // 8 MB  (total 16 MB)

    // pooled -> buf0 (rows 0..4095 side a, 4096..8191 side b)
    pool_kernel<<<8192, 128, 0, stream>>>(ids_a, ids_b, mask_a, mask_b, W_emb, buf0);

    // X1 = tanh(P @ enc_w1 + b1) -> buf1   [8192,512] x [512,512]
    gemm_mfma<<<dim3(8, 64), 256, 0, stream>>>(
        buf0, buf0, 512, enc_w1, enc_b1, buf1, 512, 512, Wdet, Mdet);

    // X2 = tanh(X1 @ enc_w2 + b2) -> buf0
    gemm_mfma<<<dim3(8, 64), 256, 0, stream>>>(
        buf1, buf1, 512, enc_w2, enc_b2, buf0, 512, 512, Wdet, Mdet);

    // H = tanh([va | vb] @ cls_w1 + b1) -> buf1   [4096,1024] x [1024,512]
    gemm_mfma<<<dim3(8, 32), 256, 0, stream>>>(
        buf0, buf0 + (size_t)4096 * 512, 512, cls_w1, cls_b1, buf1, 512, 1024, Wdet, Mdet);

    // logits -> d_out (f32)
    logits_kernel<<<4096, 64, 0, stream>>>(buf1, cls_w2, cls_b2, (float*)d_out, Wdet, Mdet);
}

// Round 7
// 383.550 us; speedup vs baseline: 1.3526x; 1.0550x over previous
//
#include <hip/hip_runtime.h>

// SemNN — twin-tower masked-pool encoder + classifier.
// B=4096, S=128, D=512, VOCAB=50000, NUM_LABELS=3.
// Confirmed: float inputs bf16 (detector keeps f32 fallback), ids int32,
// masks int-like, OUTPUT f32. ws usage: exactly 16 MB.
//
// Round 7: round-6 MFMA GEMM was 77us (56 TF) because BOTH staging loads were
// 64-lane gathers (32 rows x 8B per instruction). This round:
//  * A-staging: 16B/lane, 4 lanes/row -> full 64B lines. B-staging: 16B/lane,
//    8 lanes cover 128B of one k-row; transpose happens at LDS-write with a
//    16B-chunk rotate swizzle (chunk=(k>>3 + n>>3)&3) -> 4-way writes,
//    conflict-free b128 fragment reads.
//  * Register prefetch of k+1 tiles issued before the MFMA phase.
//  * Grid: blockIdx.x = m-tile so the 8 n-tiles of an m-tile land on one XCD
//    (linear id = x + 64*y, 64*y % 8 == 0) -> A fetched ~once per XCD.
//  * pool: one wave reads a whole 1KB row per instruction (uint4/lane),
//    waves split tokens, LDS combine. logits: uint4 h-loads.

typedef unsigned short u16;
typedef __attribute__((ext_vector_type(8))) short short8;
typedef __attribute__((ext_vector_type(4))) float f32x4;

__device__ __forceinline__ float bfu2f(u16 u) {
    union { unsigned int i; float f; } v;
    v.i = ((unsigned int)u) << 16;
    return v.f;
}

__device__ __forceinline__ u16 f2bfu(float f) {
    union { float f; unsigned int i; } v;
    v.f = f;
    unsigned int x = v.i;
    x += 0x7fffu + ((x >> 16) & 1u);   // RNE
    return (u16)(x >> 16);
}

// Wave-collective dtype detection; every lane returns flags:
//   bit0: float tensors are bf16 (vs f32); bits2-3: mask type
//   0=int32, 1=byte-bool, 2=bf16, 3=f32
__device__ __forceinline__ int detect_wave(const u16* __restrict__ W,
                                           const unsigned int* __restrict__ m,
                                           int lane)
{
    int cnt = 0;
    int w01 = 1, b01 = 1, lo16 = 0;
    #pragma unroll
    for (int j = lane; j < 256; j += 64) {
        u16 u = W[1024 + 2 * j];
        int e = (u >> 7) & 0xFF;
        cnt += (e >= 0x6A && e <= 0x7E) ? 1 : 0;
        unsigned int v = m[j];
        w01 &= (v <= 1u) ? 1 : 0;
        b01 &= ((v & ~0x01010101u) == 0u) ? 1 : 0;
        lo16 |= ((v & 0xFFFFu) == 0x3F80u) ? 1 : 0;
    }
    #pragma unroll
    for (int off = 32; off > 0; off >>= 1) {
        cnt  += __shfl_down(cnt, off);
        w01  &= __shfl_down(w01, off);
        b01  &= __shfl_down(b01, off);
        lo16 |= __shfl_down(lo16, off);
    }
    int mtype;
    if (w01)        mtype = 0;
    else if (b01)   mtype = 1;
    else if (lo16)  mtype = 2;
    else            mtype = 3;
    int fl = ((cnt >= 128) ? 1 : 0) | (mtype << 2);
    return __shfl(fl, 0);
}

__device__ __forceinline__ int mask_nonzero(const void* __restrict__ msk,
                                            int idx, int mtype)
{
    switch (mtype) {
        case 0:  return ((const int*)msk)[idx] != 0;
        case 1:  return ((const unsigned char*)msk)[idx] != 0;
        case 2:  return ((const u16*)msk)[idx] != 0;
        default: return ((const unsigned int*)msk)[idx] != 0u;
    }
}

// ---------------------------------------------------------------------------
// Kernel 1: embedding gather + masked sum-pool -> P (bf16) [8192,512].
// Block = (side,row), 128 threads = 2 waves. Each wave reads whole 1KB rows
// (lane owns 16B = 8 bf16 cols), waves split tokens, LDS combine at end.
// ---------------------------------------------------------------------------
__global__ __launch_bounds__(128) void pool_kernel(
    const int* __restrict__ ids_a, const int* __restrict__ ids_b,
    const void* __restrict__ mask_a, const void* __restrict__ mask_b,
    const void* __restrict__ W, u16* __restrict__ P)
{
    __shared__ int s_ids[128];
    __shared__ int s_cnt;
    __shared__ int s_flags;
    __shared__ float sP[512];
    const int t = threadIdx.x;
    const int w = t >> 6;
    const int lane = t & 63;

    if (t == 0) s_cnt = 0;
    if (t < 64) {
        int fl = detect_wave((const u16*)W, (const unsigned int*)mask_a, t);
        if (t == 0) s_flags = fl;
    }
    __syncthreads();
    const int  flags = s_flags;
    const bool isbf  = (flags & 1) != 0;
    const int  mtype = (flags >> 2) & 3;

    const int row  = blockIdx.x & 4095;
    const int side = blockIdx.x >> 12;
    const int* __restrict__ ids = side ? ids_b : ids_a;
    const void* __restrict__ msk = side ? mask_b : mask_a;

    int id = ids[row * 128 + t];
    int mk = mask_nonzero(msk, row * 128 + t, mtype);
    if (mk) {
        int idx = atomicAdd(&s_cnt, 1);
        s_ids[idx] = id;
    }
    __syncthreads();
    const int cnt = s_cnt;

    float acc[8] = {};
    if (isbf) {
        const u16* Wb = (const u16*)W;
        int j = w;
        for (; j + 6 < cnt; j += 8) {
            union { uint4 v; u16 s[8]; } r0, r1, r2, r3;
            r0.v = *(const uint4*)(Wb + (size_t)s_ids[j + 0] * 512 + lane * 8);
            r1.v = *(const uint4*)(Wb + (size_t)s_ids[j + 2] * 512 + lane * 8);
            r2.v = *(const uint4*)(Wb + (size_t)s_ids[j + 4] * 512 + lane * 8);
            r3.v = *(const uint4*)(Wb + (size_t)s_ids[j + 6] * 512 + lane * 8);
            #pragma unroll
            for (int i = 0; i < 8; ++i)
                acc[i] += bfu2f(r0.s[i]) + bfu2f(r1.s[i]) +
                          bfu2f(r2.s[i]) + bfu2f(r3.s[i]);
        }
        for (; j < cnt; j += 2) {
            union { uint4 v; u16 s[8]; } r;
            r.v = *(const uint4*)(Wb + (size_t)s_ids[j] * 512 + lane * 8);
            #pragma unroll
            for (int i = 0; i < 8; ++i) acc[i] += bfu2f(r.s[i]);
        }
    } else {
        const float* Wf = (const float*)W;
        for (int j = w; j < cnt; j += 2) {
            const float* rp = Wf + (size_t)s_ids[j] * 512 + lane * 8;
            float4 a = *(const float4*)(rp + 0);
            float4 b = *(const float4*)(rp + 4);
            acc[0] += a.x; acc[1] += a.y; acc[2] += a.z; acc[3] += a.w;
            acc[4] += b.x; acc[5] += b.y; acc[6] += b.z; acc[7] += b.w;
        }
    }

    if (w == 0) {
        #pragma unroll
        for (int i = 0; i < 8; ++i) sP[lane * 8 + i] = acc[i];
    }
    __syncthreads();
    if (w == 1) {
        union { uint4 v; u16 s[8]; } o;
        #pragma unroll
        for (int i = 0; i < 8; ++i)
            o.s[i] = f2bfu(acc[i] + sP[lane * 8 + i]);
        *(uint4*)(P + (size_t)blockIdx.x * 512 + lane * 8) = o.v;
    }
}

// ---------------------------------------------------------------------------
// Kernel 2: bf16 MFMA GEMM + bias + tanh.  C = tanh(Acat @ B + bias).
// Acat[m,k] = A[m*512+k] (k<K1) else A2[m*512+(k-K1)].
// Block tile 128(M) x 64(N), BK=32, 256 thr = 4 waves (2x2), wave 64x32.
// MFMA 16x16x32 bf16; layouts per m89/m91. LDS rows 40 u16 (80B).
// Bs uses 16B-chunk rotate swizzle: phys_chunk = (k_chunk + (n>>3)) & 3.
// Register prefetch of next k-step issued before MFMA phase.
// grid: blockIdx.x = m-tile (XCD sharing), blockIdx.y = n-tile.
// ---------------------------------------------------------------------------
__global__ __launch_bounds__(256) void gemm_mfma(
    const u16* __restrict__ A, const u16* __restrict__ A2, int K1,
    const void* __restrict__ B, const void* __restrict__ bias,
    u16* __restrict__ C, int N, int K,
    const u16* __restrict__ Wdet, const unsigned int* __restrict__ Mdet)
{
    __shared__ __align__(16) u16 As[128 * 40];
    __shared__ __align__(16) u16 Bs[64 * 40];
    __shared__ int s_flags;

    const int tid  = threadIdx.x;
    const int lane = tid & 63;

    if (tid < 64) {
        int fl = detect_wave(Wdet, Mdet, tid);
        if (tid == 0) s_flags = fl;
    }
    __syncthreads();
    const bool isbf = (s_flags & 1) != 0;

    const int m0 = blockIdx.x * 128;
    const int n0 = blockIdx.y * 64;

    const int wid = tid >> 6;
    const int wm  = (wid & 1) * 64;
    const int wn  = (wid >> 1) * 32;

    // A staging: 16B/lane, 4 lanes per row (full 64B line per 4 lanes).
    const int ar = tid >> 2;          // 0..63 (and +64 for second row-block)
    const int ak = (tid & 3) * 8;     // k-offset 0,8,16,24
    // B staging: 16B/lane, 8 lanes cover 128B of row k0+bk.
    const int bk = tid >> 3;          // 0..31
    const int jn = tid & 7;           // n-chunk (8 cols each)
    const int nb = jn * 8;
    const int bofs = (((bk >> 3) + jn) & 3) * 8 + (bk & 7);  // swizzled dest

    const int lm = lane & 15;
    const int kq = lane >> 4;         // k-chunk 0..3
    const int kc = kq * 8;

    f32x4 acc[4][2];
    #pragma unroll
    for (int i = 0; i < 4; ++i)
        #pragma unroll
        for (int j = 0; j < 2; ++j)
            acc[i][j] = (f32x4){0.f, 0.f, 0.f, 0.f};

    uint4 ra0, ra1;
    u16 rb[8];

    auto fetch = [&](int k0) {
        const int kg = k0 + ak;
        const u16* Ap0 = (kg < K1) ? (A  + (size_t)(m0 + ar) * 512 + kg)
                                   : (A2 + (size_t)(m0 + ar) * 512 + (kg - K1));
        const u16* Ap1 = (kg < K1) ? (A  + (size_t)(m0 + ar + 64) * 512 + kg)
                                   : (A2 + (size_t)(m0 + ar + 64) * 512 + (kg - K1));
        ra0 = *(const uint4*)Ap0;
        ra1 = *(const uint4*)Ap1;
        if (isbf) {
            union { uint4 v; u16 s[8]; } ub;
            ub.v = *(const uint4*)((const u16*)B + (size_t)(k0 + bk) * N + n0 + nb);
            #pragma unroll
            for (int i = 0; i < 8; ++i) rb[i] = ub.s[i];
        } else {
            const float* Bp = (const float*)B + (size_t)(k0 + bk) * N + n0 + nb;
            float4 b0 = *(const float4*)(Bp + 0);
            float4 b1 = *(const float4*)(Bp + 4);
            rb[0] = f2bfu(b0.x); rb[1] = f2bfu(b0.y); rb[2] = f2bfu(b0.z); rb[3] = f2bfu(b0.w);
            rb[4] = f2bfu(b1.x); rb[5] = f2bfu(b1.y); rb[6] = f2bfu(b1.z); rb[7] = f2bfu(b1.w);
        }
    };

    fetch(0);
    for (int k0 = 0; k0 < K; k0 += 32) {
        if (k0) __syncthreads();           // protect prev frag reads (WAR)
        *(uint4*)&As[ar * 40 + ak]        = ra0;
        *(uint4*)&As[(ar + 64) * 40 + ak] = ra1;
        #pragma unroll
        for (int i = 0; i < 8; ++i)
            Bs[(nb + i) * 40 + bofs] = rb[i];
        __syncthreads();

        if (k0 + 32 < K) fetch(k0 + 32);   // prefetch overlaps frag+MFMA

        short8 af[4], bf[2];
        #pragma unroll
        for (int i = 0; i < 4; ++i)
            af[i] = *(const short8*)&As[(wm + i * 16 + lm) * 40 + kc];
        #pragma unroll
        for (int j = 0; j < 2; ++j) {
            const int n = wn + j * 16 + lm;
            const int ch = ((kq + (n >> 3)) & 3) * 8;
            bf[j] = *(const short8*)&Bs[n * 40 + ch];
        }
        #pragma unroll
        for (int i = 0; i < 4; ++i)
            #pragma unroll
            for (int j = 0; j < 2; ++j)
                acc[i][j] = __builtin_amdgcn_mfma_f32_16x16x32_bf16(
                    af[i], bf[j], acc[i][j], 0, 0, 0);
    }

    // epilogue: bias + tanh + bf16 store
    #pragma unroll
    for (int j = 0; j < 2; ++j) {
        const int n = n0 + wn + j * 16 + lm;
        const float bsv = isbf ? bfu2f(((const u16*)bias)[n])
                               : ((const float*)bias)[n];
        #pragma unroll
        for (int i = 0; i < 4; ++i) {
            #pragma unroll
            for (int r = 0; r < 4; ++r) {
                const int m = m0 + wm + i * 16 + kq * 4 + r;
                C[(size_t)m * N + n] = f2bfu(tanhf(acc[i][j][r] + bsv));
            }
        }
    }
}

// ---------------------------------------------------------------------------
// Kernel 3: logits GEMV  out[m,0:3] = H[m,:] @ W2 + b2 -> f32 out.
// One wave per row; lane owns 8 k's (16B vector load of H).
// ---------------------------------------------------------------------------
__global__ __launch_bounds__(64) void logits_kernel(
    const u16* __restrict__ H, const void* __restrict__ W2,
    const void* __restrict__ b2, float* __restrict__ out,
    const u16* __restrict__ Wdet, const unsigned int* __restrict__ Mdet)
{
    const int lane = threadIdx.x;
    const int fl = detect_wave(Wdet, Mdet, lane);
    const bool isbf = (fl & 1) != 0;

    const int m = blockIdx.x;
    union { uint4 v; u16 s[8]; } h;
    h.v = *(const uint4*)(H + (size_t)m * 512 + lane * 8);

    float a0 = 0.f, a1 = 0.f, a2 = 0.f;
    #pragma unroll
    for (int i = 0; i < 8; ++i) {
        const int k = lane * 8 + i;
        float x = bfu2f(h.s[i]);
        float w0, w1, w2;
        if (isbf) {
            const u16* Wb = (const u16*)W2;
            w0 = bfu2f(Wb[k * 3 + 0]); w1 = bfu2f(Wb[k * 3 + 1]); w2 = bfu2f(Wb[k * 3 + 2]);
        } else {
            const float* Wf = (const float*)W2;
            w0 = Wf[k * 3 + 0]; w1 = Wf[k * 3 + 1]; w2 = Wf[k * 3 + 2];
        }
        a0 += x * w0; a1 += x * w1; a2 += x * w2;
    }
    #pragma unroll
    for (int off = 32; off > 0; off >>= 1) {
        a0 += __shfl_down(a0, off);
        a1 += __shfl_down(a1, off);
        a2 += __shfl_down(a2, off);
    }
    if (lane == 0) {
        float b0, b1, b2v;
        if (isbf) {
            const u16* bb = (const u16*)b2;
            b0 = bfu2f(bb[0]); b1 = bfu2f(bb[1]); b2v = bfu2f(bb[2]);
        } else {
            const float* bf = (const float*)b2;
            b0 = bf[0]; b1 = bf[1]; b2v = bf[2];
        }
        out[m * 3 + 0] = a0 + b0;
        out[m * 3 + 1] = a1 + b1;
        out[m * 3 + 2] = a2 + b2v;
    }
}

// ---------------------------------------------------------------------------
extern "C" void kernel_launch(void* const* d_in, const int* in_sizes, int n_in,
                              void* d_out, int out_size, void* d_ws, size_t ws_size,
                              hipStream_t stream)
{
    const int* ids_a  = (const int*)d_in[0];
    const int* ids_b  = (const int*)d_in[1];
    const void* mask_a = d_in[2];
    const void* mask_b = d_in[3];
    const void* W_emb  = d_in[4];
    const void* enc_w1 = d_in[5];
    const void* enc_b1 = d_in[6];
    const void* enc_w2 = d_in[7];
    const void* enc_b2 = d_in[8];
    const void* cls_w1 = d_in[9];
    const void* cls_b1 = d_in[10];
    const void* cls_w2 = d_in[11];
    const void* cls_b2 = d_in[12];

    const u16* Wdet = (const u16*)W_emb;
    const unsigned int* Mdet = (const unsigned int*)mask_a;

    u16* buf0 = (u16*)d_ws;                          // 8192*512 bf16 = 8 MB
    u16* buf1 = buf0 + (size_t)8192 * 512;           // 8 MB  (total 16 MB)

    // pooled -> buf0 (rows 0..4095 side a, 4096..8191 side b)
    pool_kernel<<<8192, 128, 0, stream>>>(ids_a, ids_b, mask_a, mask_b, W_emb, buf0);

    // X1 = tanh(P @ enc_w1 + b1) -> buf1   [8192,512] x [512,512]
    gemm_mfma<<<dim3(64, 8), 256, 0, stream>>>(
        buf0, buf0, 512, enc_w1, enc_b1, buf1, 512, 512, Wdet, Mdet);

    // X2 = tanh(X1 @ enc_w2 + b2) -> buf0
    gemm_mfma<<<dim3(64, 8), 256, 0, stream>>>(
        buf1, buf1, 512, enc_w2, enc_b2, buf0, 512, 512, Wdet, Mdet);

    // H = tanh([va | vb] @ cls_w1 + b1) -> buf1   [4096,1024] x [1024,512]
    gemm_mfma<<<dim3(32, 8), 256, 0, stream>>>(
        buf0, buf0 + (size_t)4096 * 512, 512, cls_w1, cls_b1, buf1, 512, 1024, Wdet, Mdet);

    // logits -> d_out (f32)
    logits_kernel<<<4096, 64, 0, stream>>>(buf1, cls_w2, cls_b2, (float*)d_out, Wdet, Mdet);
}

// Round 8
// 376.070 us; speedup vs baseline: 1.3795x; 1.0199x over previous
//
#include <hip/hip_runtime.h>

// SemNN — twin-tower masked-pool encoder + classifier.
// B=4096, S=128, D=512, VOCAB=50000, NUM_LABELS=3.
// Confirmed: float inputs bf16 (detector keeps f32 fallback), ids int32,
// masks int-like, OUTPUT f32. ws usage: exactly 16 MB.
//
// Round 8:
//  * pool split into two dispatches (side a / side b, ~80us each) so the
//    ~70us GEMM dispatches can surface in the top-5 profile with counters.
//    Pool itself is at a measured BW floor (3 structurally different
//    versions all hit 161us / 3.27 TB/s / 508MB = logical-minimum fetch).
//  * gemm K-loop specialized via template<ISBF>: round-7 carried both bf16
//    and f32 staging paths INSIDE the hot loop (register pressure = sum of
//    paths, scheduling pessimism). Now one constexpr path per instantiation,
//    selected per-block after wave-0 detection. __launch_bounds__(256,2)
//    caps VGPR at 256.
//  * epilogue tanh via v_exp_f32 (hw exp2) instead of libm tanhf.

typedef unsigned short u16;
typedef __attribute__((ext_vector_type(8))) short short8;
typedef __attribute__((ext_vector_type(4))) float f32x4;

__device__ __forceinline__ float bfu2f(u16 u) {
    union { unsigned int i; float f; } v;
    v.i = ((unsigned int)u) << 16;
    return v.f;
}

__device__ __forceinline__ u16 f2bfu(float f) {
    union { float f; unsigned int i; } v;
    v.f = f;
    unsigned int x = v.i;
    x += 0x7fffu + ((x >> 16) & 1u);   // RNE
    return (u16)(x >> 16);
}

// tanh(x) = (e^{2x}-1)/(e^{2x}+1) using hw exp2; |x| clamped so e stays
// finite (x in [-15,15] -> exp2 arg <= 43.3). ~1e-7 rel error, plenty for
// bf16-rounded outputs.
__device__ __forceinline__ float fast_tanh(float x) {
    float xc = fminf(fmaxf(x, -15.f), 15.f);
    float e = __builtin_amdgcn_exp2f(xc * 2.885390082f);  // 2*log2(e)*x
    return (e - 1.f) / (e + 1.f);
}

// Wave-collective dtype detection; every lane returns flags:
//   bit0: float tensors are bf16 (vs f32); bits2-3: mask type
//   0=int32, 1=byte-bool, 2=bf16, 3=f32
__device__ __forceinline__ int detect_wave(const u16* __restrict__ W,
                                           const unsigned int* __restrict__ m,
                                           int lane)
{
    int cnt = 0;
    int w01 = 1, b01 = 1, lo16 = 0;
    #pragma unroll
    for (int j = lane; j < 256; j += 64) {
        u16 u = W[1024 + 2 * j];
        int e = (u >> 7) & 0xFF;
        cnt += (e >= 0x6A && e <= 0x7E) ? 1 : 0;
        unsigned int v = m[j];
        w01 &= (v <= 1u) ? 1 : 0;
        b01 &= ((v & ~0x01010101u) == 0u) ? 1 : 0;
        lo16 |= ((v & 0xFFFFu) == 0x3F80u) ? 1 : 0;
    }
    #pragma unroll
    for (int off = 32; off > 0; off >>= 1) {
        cnt  += __shfl_down(cnt, off);
        w01  &= __shfl_down(w01, off);
        b01  &= __shfl_down(b01, off);
        lo16 |= __shfl_down(lo16, off);
    }
    int mtype;
    if (w01)        mtype = 0;
    else if (b01)   mtype = 1;
    else if (lo16)  mtype = 2;
    else            mtype = 3;
    int fl = ((cnt >= 128) ? 1 : 0) | (mtype << 2);
    return __shfl(fl, 0);
}

__device__ __forceinline__ int mask_nonzero(const void* __restrict__ msk,
                                            int idx, int mtype)
{
    switch (mtype) {
        case 0:  return ((const int*)msk)[idx] != 0;
        case 1:  return ((const unsigned char*)msk)[idx] != 0;
        case 2:  return ((const u16*)msk)[idx] != 0;
        default: return ((const unsigned int*)msk)[idx] != 0u;
    }
}

// ---------------------------------------------------------------------------
// Kernel 1: embedding gather + masked sum-pool for ONE side -> P [4096,512].
// 4096 blocks (one per batch row), 128 threads = 2 waves; lane owns 16B of
// the 1KB row; waves split tokens; LDS combine. At the measured gather-BW
// floor (~3.3 TB/s); split per side only for profile visibility.
// ---------------------------------------------------------------------------
__global__ __launch_bounds__(128) void pool_kernel(
    const int* __restrict__ ids, const void* __restrict__ msk,
    const void* __restrict__ W, u16* __restrict__ P,
    const unsigned int* __restrict__ Mdet)
{
    __shared__ int s_ids[128];
    __shared__ int s_cnt;
    __shared__ int s_flags;
    __shared__ float sP[512];
    const int t = threadIdx.x;
    const int w = t >> 6;
    const int lane = t & 63;

    if (t == 0) s_cnt = 0;
    if (t < 64) {
        int fl = detect_wave((const u16*)W, Mdet, t);
        if (t == 0) s_flags = fl;
    }
    __syncthreads();
    const int  flags = s_flags;
    const bool isbf  = (flags & 1) != 0;
    const int  mtype = (flags >> 2) & 3;

    const int row = blockIdx.x;

    int id = ids[row * 128 + t];
    int mk = mask_nonzero(msk, row * 128 + t, mtype);
    if (mk) {
        int idx = atomicAdd(&s_cnt, 1);
        s_ids[idx] = id;
    }
    __syncthreads();
    const int cnt = s_cnt;

    float acc[8] = {};
    if (isbf) {
        const u16* Wb = (const u16*)W;
        int j = w;
        for (; j + 6 < cnt; j += 8) {
            union { uint4 v; u16 s[8]; } r0, r1, r2, r3;
            r0.v = *(const uint4*)(Wb + (size_t)s_ids[j + 0] * 512 + lane * 8);
            r1.v = *(const uint4*)(Wb + (size_t)s_ids[j + 2] * 512 + lane * 8);
            r2.v = *(const uint4*)(Wb + (size_t)s_ids[j + 4] * 512 + lane * 8);
            r3.v = *(const uint4*)(Wb + (size_t)s_ids[j + 6] * 512 + lane * 8);
            #pragma unroll
            for (int i = 0; i < 8; ++i)
                acc[i] += bfu2f(r0.s[i]) + bfu2f(r1.s[i]) +
                          bfu2f(r2.s[i]) + bfu2f(r3.s[i]);
        }
        for (; j < cnt; j += 2) {
            union { uint4 v; u16 s[8]; } r;
            r.v = *(const uint4*)(Wb + (size_t)s_ids[j] * 512 + lane * 8);
            #pragma unroll
            for (int i = 0; i < 8; ++i) acc[i] += bfu2f(r.s[i]);
        }
    } else {
        const float* Wf = (const float*)W;
        for (int j = w; j < cnt; j += 2) {
            const float* rp = Wf + (size_t)s_ids[j] * 512 + lane * 8;
            float4 a = *(const float4*)(rp + 0);
            float4 b = *(const float4*)(rp + 4);
            acc[0] += a.x; acc[1] += a.y; acc[2] += a.z; acc[3] += a.w;
            acc[4] += b.x; acc[5] += b.y; acc[6] += b.z; acc[7] += b.w;
        }
    }

    if (w == 0) {
        #pragma unroll
        for (int i = 0; i < 8; ++i) sP[lane * 8 + i] = acc[i];
    }
    __syncthreads();
    if (w == 1) {
        union { uint4 v; u16 s[8]; } o;
        #pragma unroll
        for (int i = 0; i < 8; ++i)
            o.s[i] = f2bfu(acc[i] + sP[lane * 8 + i]);
        *(uint4*)(P + (size_t)row * 512 + lane * 8) = o.v;
    }
}

// ---------------------------------------------------------------------------
// Kernel 2: bf16 MFMA GEMM + bias + tanh.  C = tanh(Acat @ B + bias).
// Block tile 128x64, BK=32, 4 waves (2x2), wave 64x32. MFMA 16x16x32 bf16.
// LDS rows 40 u16 (80B): fragment reads/writes are at the uniform
// 8-access/bank floor (verified by enumeration). Bs rotate-swizzled chunks.
// Body is templated on ISBF so the hot loop carries exactly one dtype path.
// ---------------------------------------------------------------------------
template<bool ISBF>
__device__ __forceinline__ void gemm_body(
    const u16* __restrict__ A, const u16* __restrict__ A2, int K1,
    const void* __restrict__ Bv, const void* __restrict__ biasv,
    u16* __restrict__ C, int N, int K,
    u16* __restrict__ As, u16* __restrict__ Bs)
{
    const int tid  = threadIdx.x;
    const int lane = tid & 63;
    const int wid = tid >> 6;
    const int wm  = (wid & 1) * 64;
    const int wn  = (wid >> 1) * 32;
    const int ar = tid >> 2;
    const int ak = (tid & 3) * 8;
    const int bk = tid >> 3;
    const int jn = tid & 7;
    const int nb = jn * 8;
    const int bofs = (((bk >> 3) + jn) & 3) * 8 + (bk & 7);
    const int lm = lane & 15;
    const int kq = lane >> 4;
    const int kc = kq * 8;
    const int m0 = blockIdx.x * 128;
    const int n0 = blockIdx.y * 64;

    const u16*   Bb = (const u16*)Bv;
    const float* Bf = (const float*)Bv;

    f32x4 acc[4][2];
    #pragma unroll
    for (int i = 0; i < 4; ++i)
        #pragma unroll
        for (int j = 0; j < 2; ++j)
            acc[i][j] = (f32x4){0.f, 0.f, 0.f, 0.f};

    uint4 ra0, ra1;
    uint4 rbb;
    float4 rf0, rf1;

    // fetch(k0): coalesced A (16B/lane, 4 lanes/row) + B (16B/lane, 8/row)
    #define FETCH(k0)                                                         \
    {                                                                         \
        const int kg = (k0) + ak;                                             \
        const u16* base = (kg < K1) ? (A + kg) : (A2 + (kg - K1));            \
        ra0 = *(const uint4*)(base + (size_t)(m0 + ar) * 512);                \
        ra1 = *(const uint4*)(base + (size_t)(m0 + ar + 64) * 512);           \
        if constexpr (ISBF) {                                                 \
            rbb = *(const uint4*)(Bb + (size_t)((k0) + bk) * N + n0 + nb);    \
        } else {                                                              \
            const float* Bp = Bf + (size_t)((k0) + bk) * N + n0 + nb;         \
            rf0 = *(const float4*)(Bp + 0);                                   \
            rf1 = *(const float4*)(Bp + 4);                                   \
        }                                                                     \
    }

    FETCH(0)
    for (int k0 = 0; k0 < K; k0 += 32) {
        if (k0) __syncthreads();           // WAR: prev frag reads done
        *(uint4*)&As[ar * 40 + ak]        = ra0;
        *(uint4*)&As[(ar + 64) * 40 + ak] = ra1;
        u16 bvals[8];
        if constexpr (ISBF) {
            union { uint4 v; u16 s[8]; } ub; ub.v = rbb;
            #pragma unroll
            for (int i = 0; i < 8; ++i) bvals[i] = ub.s[i];
        } else {
            bvals[0] = f2bfu(rf0.x); bvals[1] = f2bfu(rf0.y);
            bvals[2] = f2bfu(rf0.z); bvals[3] = f2bfu(rf0.w);
            bvals[4] = f2bfu(rf1.x); bvals[5] = f2bfu(rf1.y);
            bvals[6] = f2bfu(rf1.z); bvals[7] = f2bfu(rf1.w);
        }
        #pragma unroll
        for (int i = 0; i < 8; ++i)
            Bs[(nb + i) * 40 + bofs] = bvals[i];
        __syncthreads();

        if (k0 + 32 < K) FETCH(k0 + 32)    // prefetch overlaps frag+MFMA

        short8 af[4], bf[2];
        #pragma unroll
        for (int i = 0; i < 4; ++i)
            af[i] = *(const short8*)&As[(wm + i * 16 + lm) * 40 + kc];
        #pragma unroll
        for (int j = 0; j < 2; ++j) {
            const int n = wn + j * 16 + lm;
            const int ch = ((kq + (n >> 3)) & 3) * 8;
            bf[j] = *(const short8*)&Bs[n * 40 + ch];
        }
        #pragma unroll
        for (int i = 0; i < 4; ++i)
            #pragma unroll
            for (int j = 0; j < 2; ++j)
                acc[i][j] = __builtin_amdgcn_mfma_f32_16x16x32_bf16(
                    af[i], bf[j], acc[i][j], 0, 0, 0);
    }
    #undef FETCH

    // epilogue: bias + tanh + bf16 store
    #pragma unroll
    for (int j = 0; j < 2; ++j) {
        const int n = n0 + wn + j * 16 + lm;
        const float bsv = ISBF ? bfu2f(((const u16*)biasv)[n])
                               : ((const float*)biasv)[n];
        #pragma unroll
        for (int i = 0; i < 4; ++i) {
            #pragma unroll
            for (int r = 0; r < 4; ++r) {
                const int m = m0 + wm + i * 16 + kq * 4 + r;
                C[(size_t)m * N + n] = f2bfu(fast_tanh(acc[i][j][r] + bsv));
            }
        }
    }
}

__global__ __launch_bounds__(256, 2) void gemm_mfma(
    const u16* __restrict__ A, const u16* __restrict__ A2, int K1,
    const void* __restrict__ B, const void* __restrict__ bias,
    u16* __restrict__ C, int N, int K,
    const u16* __restrict__ Wdet, const unsigned int* __restrict__ Mdet)
{
    __shared__ __align__(16) u16 As[128 * 40];
    __shared__ __align__(16) u16 Bs[64 * 40];
    __shared__ int s_flags;

    if (threadIdx.x < 64) {
        int fl = detect_wave(Wdet, Mdet, threadIdx.x);
        if (threadIdx.x == 0) s_flags = fl;
    }
    __syncthreads();
    if (s_flags & 1) gemm_body<true >(A, A2, K1, B, bias, C, N, K, As, Bs);
    else             gemm_body<false>(A, A2, K1, B, bias, C, N, K, As, Bs);
}

// ---------------------------------------------------------------------------
// Kernel 3: logits GEMV  out[m,0:3] = H[m,:] @ W2 + b2 -> f32 out.
// ---------------------------------------------------------------------------
__global__ __launch_bounds__(64) void logits_kernel(
    const u16* __restrict__ H, const void* __restrict__ W2,
    const void* __restrict__ b2, float* __restrict__ out,
    const u16* __restrict__ Wdet, const unsigned int* __restrict__ Mdet)
{
    const int lane = threadIdx.x;
    const int fl = detect_wave(Wdet, Mdet, lane);
    const bool isbf = (fl & 1) != 0;

    const int m = blockIdx.x;
    union { uint4 v; u16 s[8]; } h;
    h.v = *(const uint4*)(H + (size_t)m * 512 + lane * 8);

    float a0 = 0.f, a1 = 0.f, a2 = 0.f;
    #pragma unroll
    for (int i = 0; i < 8; ++i) {
        const int k = lane * 8 + i;
        float x = bfu2f(h.s[i]);
        float w0, w1, w2;
        if (isbf) {
            const u16* Wb = (const u16*)W2;
            w0 = bfu2f(Wb[k * 3 + 0]); w1 = bfu2f(Wb[k * 3 + 1]); w2 = bfu2f(Wb[k * 3 + 2]);
        } else {
            const float* Wf = (const float*)W2;
            w0 = Wf[k * 3 + 0]; w1 = Wf[k * 3 + 1]; w2 = Wf[k * 3 + 2];
        }
        a0 += x * w0; a1 += x * w1; a2 += x * w2;
    }
    #pragma unroll
    for (int off = 32; off > 0; off >>= 1) {
        a0 += __shfl_down(a0, off);
        a1 += __shfl_down(a1, off);
        a2 += __shfl_down(a2, off);
    }
    if (lane == 0) {
        float b0, b1, b2v;
        if (isbf) {
            const u16* bb = (const u16*)b2;
            b0 = bfu2f(bb[0]); b1 = bfu2f(bb[1]); b2v = bfu2f(bb[2]);
        } else {
            const float* bf = (const float*)b2;
            b0 = bf[0]; b1 = bf[1]; b2v = bf[2];
        }
        out[m * 3 + 0] = a0 + b0;
        out[m * 3 + 1] = a1 + b1;
        out[m * 3 + 2] = a2 + b2v;
    }
}

// ---------------------------------------------------------------------------
extern "C" void kernel_launch(void* const* d_in, const int* in_sizes, int n_in,
                              void* d_out, int out_size, void* d_ws, size_t ws_size,
                              hipStream_t stream)
{
    const int* ids_a  = (const int*)d_in[0];
    const int* ids_b  = (const int*)d_in[1];
    const void* mask_a = d_in[2];
    const void* mask_b = d_in[3];
    const void* W_emb  = d_in[4];
    const void* enc_w1 = d_in[5];
    const void* enc_b1 = d_in[6];
    const void* enc_w2 = d_in[7];
    const void* enc_b2 = d_in[8];
    const void* cls_w1 = d_in[9];
    const void* cls_b1 = d_in[10];
    const void* cls_w2 = d_in[11];
    const void* cls_b2 = d_in[12];

    const u16* Wdet = (const u16*)W_emb;
    const unsigned int* Mdet = (const unsigned int*)mask_a;

    u16* buf0 = (u16*)d_ws;                          // 8192*512 bf16 = 8 MB
    u16* buf1 = buf0 + (size_t)8192 * 512;           // 8 MB  (total 16 MB)

    // pooled -> buf0 (rows 0..4095 side a, 4096..8191 side b); split per side
    pool_kernel<<<4096, 128, 0, stream>>>(ids_a, mask_a, W_emb, buf0, Mdet);
    pool_kernel<<<4096, 128, 0, stream>>>(ids_b, mask_b, W_emb,
                                          buf0 + (size_t)4096 * 512, Mdet);

    // X1 = tanh(P @ enc_w1 + b1) -> buf1   [8192,512] x [512,512]
    gemm_mfma<<<dim3(64, 8), 256, 0, stream>>>(
        buf0, buf0, 512, enc_w1, enc_b1, buf1, 512, 512, Wdet, Mdet);

    // X2 = tanh(X1 @ enc_w2 + b2) -> buf0
    gemm_mfma<<<dim3(64, 8), 256, 0, stream>>>(
        buf1, buf1, 512, enc_w2, enc_b2, buf0, 512, 512, Wdet, Mdet);

    // H = tanh([va | vb] @ cls_w1 + b1) -> buf1   [4096,1024] x [1024,512]
    gemm_mfma<<<dim3(32, 8), 256, 0, stream>>>(
        buf0, buf0 + (size_t)4096 * 512, 512, cls_w1, cls_b1, buf1, 512, 1024, Wdet, Mdet);

    // logits -> d_out (f32)
    logits_kernel<<<4096, 64, 0, stream>>>(buf1, cls_w2, cls_b2, (float*)d_out, Wdet, Mdet);
}